// Round 1
// baseline (1058.828 us; speedup 1.0000x reference)
//
#include <hip/hip_runtime.h>
#include <stdint.h>

#define HID   128
#define OUT   4096
#define NWG   8           // persistent EP workgroups, slice = 512 cols each
#define SLICE 512         // OUT / NWG
#define NT    512
#define NXB   128         // one-shot xW1 worker blocks
#define RPX   512         // rows per xW1 block (65536 / 128)

typedef unsigned long long u64;

__device__ __forceinline__ u64 pk(uint32_t tag, float v) {
  return ((u64)tag << 32) | (u64)__float_as_uint(v);
}

// Workspace layout:
//   pbuf  [2][NWG][HID] u64 @ 0       primary h-partials (same-XCD L2 domain, sc0)
//   pshad [2][NWG][HID] u64 @ 16384   shadow h-partials (agent/MALL domain, sc0 sc1)
//   xw1p  [NXB][HID]    u64 @ 32768   xW1 partials (agent domain, unchanged)
//   ctl   int[16]           @ 163840  election state (memset 0 each launch)
//     ctl[0] = chosen_xcd+1 (0 = none), ctl[1] = worker claim ctr, ctl[2..9] = per-XCD count

__global__ __launch_bounds__(NT, 1) void k_all(
    const float* __restrict__ x,
    const float* __restrict__ W1,
    const float* __restrict__ W2,
    const float* __restrict__ b_h,
    const float* __restrict__ b_out,
    const float* __restrict__ h0,
    const float* __restrict__ o0,
    const int* __restrict__ n_iter_p,
    const float* __restrict__ eps_p,
    u64* __restrict__ pbuf,
    u64* __restrict__ pshad,
    u64* __restrict__ xw1p,
    int* __restrict__ ctl,
    float* __restrict__ out) {

  __shared__ __attribute__((aligned(16))) float red[8 * SLICE];  // 16 KB
  __shared__ __attribute__((aligned(16))) float rh_s[HID];
  __shared__ __attribute__((aligned(16))) float ro_s[SLICE];
  __shared__ int s_role;

  const int t = threadIdx.x;

  // ---------------- XCD election: co-locate the 8 EP WGs on ONE XCD ---------------
  // All 136 blocks are co-resident (<=2 blocks/CU over 256 CUs), so some XCD's
  // counter is guaranteed to reach 8 -> no deadlock. Blocks 0..7 (by arrival) of
  // the first XCD to assemble 8 become the EP group; everyone else claims a
  // unique xW1 worker id (exactly 136-8 = 128 workers).
  if (t == 0) {
    const uint32_t xcd =
        (uint32_t)__builtin_amdgcn_s_getreg((31 << 11) | 20) & 7u;  // HW_REG_XCC_ID (id 20)
    const int idx = __hip_atomic_fetch_add(&ctl[2 + (int)xcd], 1, __ATOMIC_RELAXED,
                                           __HIP_MEMORY_SCOPE_AGENT);
    if (idx == NWG - 1) {  // this XCD just assembled its 8th block: try to claim
      int expected = 0;
      __hip_atomic_compare_exchange_strong(&ctl[0], &expected, (int)xcd + 1,
                                           __ATOMIC_RELAXED, __ATOMIC_RELAXED,
                                           __HIP_MEMORY_SCOPE_AGENT);
    }
    int ch;
    while ((ch = __hip_atomic_load(&ctl[0], __ATOMIC_RELAXED,
                                   __HIP_MEMORY_SCOPE_AGENT)) == 0)
      __builtin_amdgcn_s_sleep(8);
    s_role = ((int)xcd + 1 == ch && idx < NWG)
                 ? idx
                 : NWG + __hip_atomic_fetch_add(&ctl[1], 1, __ATOMIC_RELAXED,
                                                __HIP_MEMORY_SCOPE_AGENT);
  }
  __syncthreads();
  const int role = s_role;

  if (role >= NWG) {
    // ---------------- xW1 worker: partial of clip(x,0,1) @ W1 over 512 rows ------
    const int b = role - NWG;           // 0..127, unique
    const int c4 = (t & 31) * 4;
    const int rseg = t >> 5;            // 0..15
    const int r0 = b * RPX + rseg * 32;
    float4 acc = make_float4(0.f, 0.f, 0.f, 0.f);
#pragma unroll 8
    for (int k = 0; k < 32; ++k) {
      const int r = r0 + k;
      const float rx = fminf(fmaxf(x[r], 0.f), 1.f);
      const float4 wv = *(const float4*)&W1[(size_t)r * HID + c4];
      acc.x = fmaf(rx, wv.x, acc.x); acc.y = fmaf(rx, wv.y, acc.y);
      acc.z = fmaf(rx, wv.z, acc.z); acc.w = fmaf(rx, wv.w, acc.w);
    }
    *(float4*)&red[rseg * HID + c4] = acc;
    __syncthreads();
    if (t < HID) {
      float s = 0.f;
#pragma unroll
      for (int k = 0; k < 16; k += 4)
        s += (red[k*HID + t] + red[(k+1)*HID + t]) + (red[(k+2)*HID + t] + red[(k+3)*HID + t]);
      __hip_atomic_store(&xw1p[b * HID + t], pk(1u, s),
                         __ATOMIC_RELAXED, __HIP_MEMORY_SCOPE_AGENT);
    }
    return;
  }

  // ---------------- persistent EP workgroup (all 8 on the SAME XCD) ---------------
  const int wg = role;
  const int cg = t & 63;               // lane id; owns cols cg + 64*k (k=0..7)
  const int rg = t >> 6;               // wave id; owns rows rg*16 .. rg*16+15
  const int n_iter = *n_iter_p;
  const float eps  = *eps_p;

  // ---- W2 chunk into registers: w2[r][k] = W2[rg*16+r][wg*512 + cg + 64k] ----
  float w2[16][8];
  {
    const float* wp = W2 + (size_t)(rg * 16) * OUT + wg * SLICE + cg;
#pragma unroll
    for (int r = 0; r < 16; ++r)
#pragma unroll
      for (int k = 0; k < 8; ++k)
        w2[r][k] = wp[(size_t)r * OUT + 64 * k];
  }
#pragma unroll
  for (int r = 0; r < 16; ++r)
    asm volatile("" : "+v"(w2[r][0]), "+v"(w2[r][1]), "+v"(w2[r][2]), "+v"(w2[r][3]),
                      "+v"(w2[r][4]), "+v"(w2[r][5]), "+v"(w2[r][6]), "+v"(w2[r][7]));

  // ---- precomputed publish / poll addresses (both parities) ----
  const int prow = wg * HID + rg * 16 + (cg >> 2);
  const u64 pubp0 = (u64)(uintptr_t)(pbuf + prow);
  const u64 pubp1 = (u64)(uintptr_t)(pbuf + NWG * HID + prow);
  const u64 pubs0 = (u64)(uintptr_t)(pshad + prow);
  const u64 pubs1 = (u64)(uintptr_t)(pshad + NWG * HID + prow);
  const u64 pol0  = (u64)(uintptr_t)(pbuf + t);             // + wi*1024B via imm offset
  const u64 pol1  = (u64)(uintptr_t)(pbuf + NWG * HID + t);

  // ---- gather xW1 partials (cross-XCD -> keep agent scope) ----
  float bhx = 0.f, hh = 0.f, mh = 0.f, vh = 0.f;
  if (t < HID) {
    float s = 0.f;
#pragma unroll 1
    for (int chk = 0; chk < 8; ++chk) {
      u64 v[16];
      for (;;) {
#pragma unroll
        for (int k = 0; k < 16; ++k)
          v[k] = __hip_atomic_load(&xw1p[(chk * 16 + k) * HID + t],
                                   __ATOMIC_RELAXED, __HIP_MEMORY_SCOPE_AGENT);
        uint32_t bad = 0u;
#pragma unroll
        for (int k = 0; k < 16; ++k) bad |= ((uint32_t)(v[k] >> 32)) ^ 1u;
        if (bad == 0u) break;
        __builtin_amdgcn_s_sleep(2);
      }
#pragma unroll
      for (int k = 0; k < 16; ++k) s += __uint_as_float((uint32_t)v[k]);
    }
    bhx = b_h[t] + s;
    hh  = h0[t];
    rh_s[t] = fminf(fmaxf(hh, 0.f), 1.f);
  }
  float oo = o0[wg * SLICE + t];       // one o-column per thread (SLICE == NT)
  float mo = 0.f, vo = 0.f;
  const float bo = b_out[wg * SLICE + t];
  ro_s[t] = fminf(fmaxf(oo, 0.f), 1.f);
  __syncthreads();

  float bp1 = 1.f, bp2 = 1.f;

  for (int it = 0; it < n_iter; ++it) {
    bp1 *= 0.9f; bp2 *= 0.999f;
    const float c1 = 1.f / (1.f - bp1);
    const float c2 = 1.f / (1.f - bp2);
    const uint32_t tag = (uint32_t)(it + 1);

    // ---- Pass B (registers): rows rg*16..+15, partial over this thread's 8 cols ----
    float aB[16];
    {
      float rov[8];
#pragma unroll
      for (int k = 0; k < 8; ++k) rov[k] = ro_s[cg + 64 * k];   // stride-1/lane, conflict-free
#pragma unroll
      for (int r = 0; r < 16; ++r) {
        float a = w2[r][0] * rov[0];
#pragma unroll
        for (int k = 1; k < 8; ++k) a = fmaf(w2[r][k], rov[k], a);
        aB[r] = a;
      }
    }
    // ---- in-wave fold: 64 lanes x 16 rows -> one row sum per lane quad ----
    {
#pragma unroll
      for (int r = 0; r < 8; ++r) {   // xor 32: 16 -> 8 rows
        const float keep = (cg & 32) ? aB[r + 8] : aB[r];
        const float send = (cg & 32) ? aB[r]     : aB[r + 8];
        aB[r] = keep + __shfl_xor(send, 32, 64);
      }
#pragma unroll
      for (int r = 0; r < 4; ++r) {   // xor 16: 8 -> 4
        const float keep = (cg & 16) ? aB[r + 4] : aB[r];
        const float send = (cg & 16) ? aB[r]     : aB[r + 4];
        aB[r] = keep + __shfl_xor(send, 16, 64);
      }
#pragma unroll
      for (int r = 0; r < 2; ++r) {   // xor 8: 4 -> 2
        const float keep = (cg & 8) ? aB[r + 2] : aB[r];
        const float send = (cg & 8) ? aB[r]     : aB[r + 2];
        aB[r] = keep + __shfl_xor(send, 8, 64);
      }
      {                               // xor 4: 2 -> 1
        const float keep = (cg & 4) ? aB[1] : aB[0];
        const float send = (cg & 4) ? aB[0] : aB[1];
        aB[0] = keep + __shfl_xor(send, 4, 64);
      }
      aB[0] += __shfl_xor(aB[0], 2, 64);   // duplicate folds
      aB[0] += __shfl_xor(aB[0], 1, 64);
    }
    // ---- publish tagged partial EARLY: primary lands in the shared XCD L2 (sc0),
    //      shadow is written through to the agent coherence point (sc0 sc1) ----
    if ((cg & 3) == 0) {
      const u64 val = pk(tag, aB[0]);
      const u64 pp  = (it & 1) ? pubp1 : pubp0;
      const u64 psd = (it & 1) ? pubs1 : pubs0;
      asm volatile("global_store_dwordx2 %0, %1, off sc0" :: "v"(pp),  "v"(val) : "memory");
      asm volatile("global_store_dwordx2 %0, %1, off sc0 sc1" :: "v"(psd), "v"(val) : "memory");
    }

    // ---- Pass A (registers, overlaps propagation): r_h @ W2 over this thread's rows ----
    {
      float aA[8] = {0.f, 0.f, 0.f, 0.f, 0.f, 0.f, 0.f, 0.f};
#pragma unroll
      for (int r = 0; r < 16; ++r) {
        const float rh = rh_s[rg * 16 + r];          // wave-uniform broadcast
#pragma unroll
        for (int k = 0; k < 8; ++k) aA[k] = fmaf(w2[r][k], rh, aA[k]);
      }
#pragma unroll
      for (int k = 0; k < 8; ++k)
        red[rg * SLICE + cg + 64 * k] = aA[k];       // stride-1/lane, conflict-free
    }
    __syncthreads();

    // ---- g_o + Adam(o): one column (= t) per thread ----
    {
      const float s = ((red[t] + red[SLICE + t]) + (red[2*SLICE + t] + red[3*SLICE + t]))
                    + ((red[4*SLICE + t] + red[5*SLICE + t]) + (red[6*SLICE + t] + red[7*SLICE + t]));
      const float ro_old = fminf(fmaxf(oo, 0.f), 1.f);
      const float g = (oo >= 0.f && oo <= 1.f) ? (ro_old - bo - s) : 0.f;
      mo = 0.9f * mo + 0.1f * g;
      vo = 0.999f * vo + 0.001f * g * g;
      oo -= eps * (mo * c1) / (sqrtf(vo * c2) + 1e-8f);
      ro_s[t] = fminf(fmaxf(oo, 0.f), 1.f);          // read next iter after end barrier
    }

    // ---- poll all 8 WGs: batched sc0 loads served by the shared XCD L2.
    //      Every 8th round reads the agent-scope shadow -> guaranteed progress even
    //      if placement/sc0 assumptions fail (then it degrades to baseline speed). ----
    if (t < HID) {
      float g0, g1, g2, g3, g4, g5, g6, g7;
      const u64 pa  = (it & 1) ? pol1 : pol0;
      const u64 pb2 = pa + 4096;
      const u64* ps = pshad + ((it & 1) ? NWG * HID : 0) + t;
      int spin = 0;
      for (;;) {
        u64 v0, v1, v2, v3, v4, v5, v6, v7;
        if (__builtin_expect((spin & 7) == 7, 0)) {
          v0 = __hip_atomic_load(ps + 0*HID, __ATOMIC_RELAXED, __HIP_MEMORY_SCOPE_AGENT);
          v1 = __hip_atomic_load(ps + 1*HID, __ATOMIC_RELAXED, __HIP_MEMORY_SCOPE_AGENT);
          v2 = __hip_atomic_load(ps + 2*HID, __ATOMIC_RELAXED, __HIP_MEMORY_SCOPE_AGENT);
          v3 = __hip_atomic_load(ps + 3*HID, __ATOMIC_RELAXED, __HIP_MEMORY_SCOPE_AGENT);
          v4 = __hip_atomic_load(ps + 4*HID, __ATOMIC_RELAXED, __HIP_MEMORY_SCOPE_AGENT);
          v5 = __hip_atomic_load(ps + 5*HID, __ATOMIC_RELAXED, __HIP_MEMORY_SCOPE_AGENT);
          v6 = __hip_atomic_load(ps + 6*HID, __ATOMIC_RELAXED, __HIP_MEMORY_SCOPE_AGENT);
          v7 = __hip_atomic_load(ps + 7*HID, __ATOMIC_RELAXED, __HIP_MEMORY_SCOPE_AGENT);
        } else {
          asm volatile(
              "global_load_dwordx2 %0, %8, off sc0\n\t"
              "global_load_dwordx2 %1, %8, off offset:1024 sc0\n\t"
              "global_load_dwordx2 %2, %8, off offset:2048 sc0\n\t"
              "global_load_dwordx2 %3, %8, off offset:3072 sc0\n\t"
              "global_load_dwordx2 %4, %9, off sc0\n\t"
              "global_load_dwordx2 %5, %9, off offset:1024 sc0\n\t"
              "global_load_dwordx2 %6, %9, off offset:2048 sc0\n\t"
              "global_load_dwordx2 %7, %9, off offset:3072 sc0\n\t"
              "s_waitcnt vmcnt(0)"
              : "=&v"(v0), "=&v"(v1), "=&v"(v2), "=&v"(v3),
                "=&v"(v4), "=&v"(v5), "=&v"(v6), "=&v"(v7)
              : "v"(pa), "v"(pb2)
              : "memory");
        }
        const uint32_t bad = (((uint32_t)(v0 >> 32)) ^ tag) | (((uint32_t)(v1 >> 32)) ^ tag)
                           | (((uint32_t)(v2 >> 32)) ^ tag) | (((uint32_t)(v3 >> 32)) ^ tag)
                           | (((uint32_t)(v4 >> 32)) ^ tag) | (((uint32_t)(v5 >> 32)) ^ tag)
                           | (((uint32_t)(v6 >> 32)) ^ tag) | (((uint32_t)(v7 >> 32)) ^ tag);
        if (bad == 0u) {
          g0 = __uint_as_float((uint32_t)v0); g1 = __uint_as_float((uint32_t)v1);
          g2 = __uint_as_float((uint32_t)v2); g3 = __uint_as_float((uint32_t)v3);
          g4 = __uint_as_float((uint32_t)v4); g5 = __uint_as_float((uint32_t)v5);
          g6 = __uint_as_float((uint32_t)v6); g7 = __uint_as_float((uint32_t)v7);
          break;
        }
        ++spin;
      }
      const float gsum = ((g0 + g1) + (g2 + g3)) + ((g4 + g5) + (g6 + g7));
      const float rh_old = fminf(fmaxf(hh, 0.f), 1.f);
      const float g = (hh >= 0.f && hh <= 1.f) ? (rh_old - bhx - gsum) : 0.f;
      mh = 0.9f * mh + 0.1f * g;
      vh = 0.999f * vh + 0.001f * g * g;
      hh -= eps * (mh * c1) / (sqrtf(vh * c2) + 1e-8f);
      rh_s[t] = fminf(fmaxf(hh, 0.f), 1.f);
    }
    __syncthreads();
  }

  out[wg * SLICE + t] = oo;
}

// ---------------- launcher ----------------------------------------------------------
extern "C" void kernel_launch(void* const* d_in, const int* in_sizes, int n_in,
                              void* d_out, int out_size, void* d_ws, size_t ws_size,
                              hipStream_t stream) {
  const float* x     = (const float*)d_in[0];
  const float* W1    = (const float*)d_in[1];
  const float* W2    = (const float*)d_in[2];
  // d_in[3] = b_in (unused by the reference)
  const float* b_h   = (const float*)d_in[4];
  const float* b_out = (const float*)d_in[5];
  const float* h0    = (const float*)d_in[6];
  const float* o0    = (const float*)d_in[7];
  const int*   nit   = (const int*)d_in[8];
  const float* eps   = (const float*)d_in[9];

  u64* pbuf  = (u64*)d_ws;                          // [2][8][128] u64 = 16 KB
  u64* pshad = (u64*)((char*)d_ws + 16384);         // [2][8][128] u64 = 16 KB
  u64* xw1p  = (u64*)((char*)d_ws + 32768);         // [128][128] u64 = 128 KB
  int* ctl   = (int*)((char*)d_ws + 163840);        // 64 B election state
  float* out = (float*)d_out;

  // pbuf/pshad/xw1p need no clearing (poisoned/stale tags never match live tags);
  // ctl must start zeroed for the election. Memset node is graph-capture safe.
  hipMemsetAsync(ctl, 0, 64, stream);
  k_all<<<dim3(NWG + NXB), dim3(NT), 0, stream>>>(x, W1, W2, b_h, b_out, h0, o0,
                                                  nit, eps, pbuf, pshad, xw1p, ctl, out);
}

// Round 2
// 551.639 us; speedup vs baseline: 1.9194x; 1.9194x over previous
//
#include <hip/hip_runtime.h>
#include <stdint.h>

#define HID   128
#define OUT   4096
#define NWG   8           // persistent EP workgroups, slice = 512 cols each
#define SLICE 512         // OUT / NWG
#define NT    512
#define NXB   128         // one-shot xW1 worker blocks
#define RPX   512         // rows per xW1 block (65536 / 128)
#define NSLOT 4           // partial-buffer ring depth (deferred check needs >2)

typedef unsigned long long u64;

__device__ __forceinline__ u64 pk(uint32_t tag, float v) {
  return ((u64)tag << 32) | (u64)__float_as_uint(v);
}

// lgkm-only barrier: syncs LDS producers/consumers WITHOUT draining vmcnt, so the
// agent-scope publish store and the prefetched poll loads stay in flight across it.
// sched_barrier(0) fences stop the compiler from moving memory ops over it (rule #18).
__device__ __forceinline__ void bar_lgkm() {
  __builtin_amdgcn_sched_barrier(0);
  asm volatile("s_waitcnt lgkmcnt(0)" ::: "memory");
  __builtin_amdgcn_s_barrier();
  __builtin_amdgcn_sched_barrier(0);
}

// blockIdx < NWG: persistent EP workgroup. blockIdx >= NWG: one-shot xW1 worker.
__global__ __launch_bounds__(NT, 1) void k_all(
    const float* __restrict__ x,
    const float* __restrict__ W1,
    const float* __restrict__ W2,
    const float* __restrict__ b_h,
    const float* __restrict__ b_out,
    const float* __restrict__ h0,
    const float* __restrict__ o0,
    const int* __restrict__ n_iter_p,
    const float* __restrict__ eps_p,
    u64* __restrict__ pbuf,   // [NSLOT][NWG][HID] tagged h-gradient partials
    u64* __restrict__ xw1p,   // [NXB][HID] tagged xW1 partials
    float* __restrict__ out) {

  __shared__ __attribute__((aligned(16))) float red[8 * SLICE];  // 16 KB
  __shared__ __attribute__((aligned(16))) float rh_s[HID];
  __shared__ __attribute__((aligned(16))) float ro_s[SLICE];

  const int t = threadIdx.x;

  if (blockIdx.x >= NWG) {
    // ---------------- xW1 worker: partial of clip(x,0,1) @ W1 over 512 rows ------
    const int b = blockIdx.x - NWG;
    const int c4 = (t & 31) * 4;
    const int rseg = t >> 5;            // 0..15
    const int r0 = b * RPX + rseg * 32;
    float4 acc = make_float4(0.f, 0.f, 0.f, 0.f);
#pragma unroll 8
    for (int k = 0; k < 32; ++k) {
      const int r = r0 + k;
      const float rx = fminf(fmaxf(x[r], 0.f), 1.f);
      const float4 wv = *(const float4*)&W1[(size_t)r * HID + c4];
      acc.x = fmaf(rx, wv.x, acc.x); acc.y = fmaf(rx, wv.y, acc.y);
      acc.z = fmaf(rx, wv.z, acc.z); acc.w = fmaf(rx, wv.w, acc.w);
    }
    *(float4*)&red[rseg * HID + c4] = acc;
    __syncthreads();
    if (t < HID) {
      float s = 0.f;
#pragma unroll
      for (int k = 0; k < 16; k += 4)
        s += (red[k*HID + t] + red[(k+1)*HID + t]) + (red[(k+2)*HID + t] + red[(k+3)*HID + t]);
      __hip_atomic_store(&xw1p[b * HID + t], pk(1u, s),
                         __ATOMIC_RELAXED, __HIP_MEMORY_SCOPE_AGENT);
    }
    return;
  }

  // ---------------- persistent EP workgroup ---------------------------------------
  const int wg = blockIdx.x;
  const int cg = t & 63;               // lane id; owns cols cg + 64*k (k=0..7)
  const int rg = t >> 6;               // wave id; owns rows rg*16 .. rg*16+15
  const int n_iter = *n_iter_p;
  const float eps  = *eps_p;

  // ---- W2 chunk into registers: w2[r][k] = W2[rg*16+r][wg*512 + cg + 64k] ----
  float w2[16][8];
  {
    const float* wp = W2 + (size_t)(rg * 16) * OUT + wg * SLICE + cg;
#pragma unroll
    for (int r = 0; r < 16; ++r)
#pragma unroll
      for (int k = 0; k < 8; ++k)
        w2[r][k] = wp[(size_t)r * OUT + 64 * k];
  }
#pragma unroll
  for (int r = 0; r < 16; ++r)
    asm volatile("" : "+v"(w2[r][0]), "+v"(w2[r][1]), "+v"(w2[r][2]), "+v"(w2[r][3]),
                      "+v"(w2[r][4]), "+v"(w2[r][5]), "+v"(w2[r][6]), "+v"(w2[r][7]));

  // ---- gather xW1 partials: BATCHED unconditional tagged loads, fixed-order sum ----
  float bhx = 0.f, hh = 0.f, mh = 0.f, vh = 0.f;
  if (t < HID) {
    float s = 0.f;
#pragma unroll 1
    for (int ch = 0; ch < 8; ++ch) {
      u64 v[16];
      for (;;) {
#pragma unroll
        for (int k = 0; k < 16; ++k)
          v[k] = __hip_atomic_load(&xw1p[(ch * 16 + k) * HID + t],
                                   __ATOMIC_RELAXED, __HIP_MEMORY_SCOPE_AGENT);
        uint32_t bad = 0u;
#pragma unroll
        for (int k = 0; k < 16; ++k) bad |= ((uint32_t)(v[k] >> 32)) ^ 1u;
        if (bad == 0u) break;
        __builtin_amdgcn_s_sleep(2);
      }
#pragma unroll
      for (int k = 0; k < 16; ++k) s += __uint_as_float((uint32_t)v[k]);
    }
    bhx = b_h[t] + s;
    hh  = h0[t];
    rh_s[t] = fminf(fmaxf(hh, 0.f), 1.f);
  }
  float oo = o0[wg * SLICE + t];       // one o-column per thread (SLICE == NT)
  float mo = 0.f, vo = 0.f;
  const float bo = b_out[wg * SLICE + t];
  ro_s[t] = fminf(fmaxf(oo, 0.f), 1.f);
  __syncthreads();

  // bp1/bp2 hold 0.9^it / 0.999^it at the deferred-check point (h uses step t1=it);
  // they advance before the o-update (o uses t1=it+1).
  float bp1 = 1.f, bp2 = 1.f;
  u64 pref[8] = {0, 0, 0, 0, 0, 0, 0, 0};   // prefetched partials for next check

  for (int it = 0; it < n_iter; ++it) {
    // ---- Pass B (registers): rows rg*16..+15, partial over this thread's 8 cols ----
    float aB[16];
    {
      float rov[8];
#pragma unroll
      for (int k = 0; k < 8; ++k) rov[k] = ro_s[cg + 64 * k];   // stride-1/lane, conflict-free
#pragma unroll
      for (int r = 0; r < 16; ++r) {
        float a = w2[r][0] * rov[0];
#pragma unroll
        for (int k = 1; k < 8; ++k) a = fmaf(w2[r][k], rov[k], a);
        aB[r] = a;
      }
    }
    // ---- in-wave fold: 64 lanes x 16 rows -> one row sum per lane quad ----
    {
#pragma unroll
      for (int r = 0; r < 8; ++r) {   // xor 32: 16 -> 8 rows
        const float keep = (cg & 32) ? aB[r + 8] : aB[r];
        const float send = (cg & 32) ? aB[r]     : aB[r + 8];
        aB[r] = keep + __shfl_xor(send, 32, 64);
      }
#pragma unroll
      for (int r = 0; r < 4; ++r) {   // xor 16: 8 -> 4
        const float keep = (cg & 16) ? aB[r + 4] : aB[r];
        const float send = (cg & 16) ? aB[r]     : aB[r + 4];
        aB[r] = keep + __shfl_xor(send, 16, 64);
      }
#pragma unroll
      for (int r = 0; r < 2; ++r) {   // xor 8: 4 -> 2
        const float keep = (cg & 8) ? aB[r + 2] : aB[r];
        const float send = (cg & 8) ? aB[r]     : aB[r + 2];
        aB[r] = keep + __shfl_xor(send, 8, 64);
      }
      {                               // xor 4: 2 -> 1
        const float keep = (cg & 4) ? aB[1] : aB[0];
        const float send = (cg & 4) ? aB[0] : aB[1];
        aB[0] = keep + __shfl_xor(send, 4, 64);
      }
      aB[0] += __shfl_xor(aB[0], 2, 64);   // duplicate folds
      aB[0] += __shfl_xor(aB[0], 1, 64);
    }

    // ---- deferred check: consume PassB(it-1) partials (prefetched last iteration).
    //      Steady state: tags already match -> zero exposed MALL latency. ----
    if (t < HID && it > 0) {
      const uint32_t tagc = (uint32_t)it;     // published at iteration it-1
      u64 v[8];
#pragma unroll
      for (int wi = 0; wi < 8; ++wi) v[wi] = pref[wi];
      uint32_t bad = 0u;
#pragma unroll
      for (int wi = 0; wi < 8; ++wi) bad |= ((uint32_t)(v[wi] >> 32)) ^ tagc;
      if (bad != 0u) {                        // prefetch was stale: retry loop
        u64* pc = pbuf + (size_t)((it - 1) & (NSLOT - 1)) * (NWG * HID);
        do {
#pragma unroll
          for (int wi = 0; wi < 8; ++wi)
            v[wi] = __hip_atomic_load(&pc[wi * HID + t],
                                      __ATOMIC_RELAXED, __HIP_MEMORY_SCOPE_AGENT);
          bad = 0u;
#pragma unroll
          for (int wi = 0; wi < 8; ++wi) bad |= ((uint32_t)(v[wi] >> 32)) ^ tagc;
          if (bad != 0u) __builtin_amdgcn_s_sleep(1);
        } while (bad != 0u);
      }
      const float gsum = ((__uint_as_float((uint32_t)v[0]) + __uint_as_float((uint32_t)v[1]))
                        + (__uint_as_float((uint32_t)v[2]) + __uint_as_float((uint32_t)v[3])))
                       + ((__uint_as_float((uint32_t)v[4]) + __uint_as_float((uint32_t)v[5]))
                        + (__uint_as_float((uint32_t)v[6]) + __uint_as_float((uint32_t)v[7])));
      const float c1h = 1.f / (1.f - bp1);    // bp1 = 0.9^it here (pre-advance)
      const float c2h = 1.f / (1.f - bp2);
      const float rh_old = fminf(fmaxf(hh, 0.f), 1.f);
      const float g = (hh >= 0.f && hh <= 1.f) ? (rh_old - bhx - gsum) : 0.f;
      mh = 0.9f * mh + 0.1f * g;
      vh = 0.999f * vh + 0.001f * g * g;
      hh -= eps * (mh * c1h) / (sqrtf(vh * c2h) + 1e-8f);
      rh_s[t] = fminf(fmaxf(hh, 0.f), 1.f);   // rh(it), consumed by Pass A below
    }

    // ---- publish tagged partial (row = rg*16 + cg/4, lanes cg%4==0).
    //      Never waited locally: bar_lgkm doesn't drain vmcnt; by the time a vmcnt(0)
    //      covers it (next iteration's retry path at worst) it is long complete. ----
    if ((cg & 3) == 0) {
      u64* pp = pbuf + (size_t)(it & (NSLOT - 1)) * (NWG * HID)
                     + wg * HID + rg * 16 + (cg >> 2);
      __hip_atomic_store(pp, pk((uint32_t)(it + 1), aB[0]),
                         __ATOMIC_RELAXED, __HIP_MEMORY_SCOPE_AGENT);
    }

    bp1 *= 0.9f; bp2 *= 0.999f;               // now 0.9^(it+1): o-update factors
    const float c1 = 1.f / (1.f - bp1);
    const float c2 = 1.f / (1.f - bp2);

    bar_lgkm();   // B1: rh_s(it) visible to all waves

    // ---- Pass A: r_h @ W2 over this thread's rows ----
    {
      float aA[8] = {0.f, 0.f, 0.f, 0.f, 0.f, 0.f, 0.f, 0.f};
#pragma unroll
      for (int r = 0; r < 16; ++r) {
        const float rh = rh_s[rg * 16 + r];          // wave-uniform broadcast
#pragma unroll
        for (int k = 0; k < 8; ++k) aA[k] = fmaf(w2[r][k], rh, aA[k]);
      }
#pragma unroll
      for (int k = 0; k < 8; ++k)
        red[rg * SLICE + cg + 64 * k] = aA[k];       // stride-1/lane, conflict-free
    }
    bar_lgkm();   // B2: red visible

    // ---- g_o + Adam(o): one column (= t) per thread ----
    {
      const float s = ((red[t] + red[SLICE + t]) + (red[2*SLICE + t] + red[3*SLICE + t]))
                    + ((red[4*SLICE + t] + red[5*SLICE + t]) + (red[6*SLICE + t] + red[7*SLICE + t]));
      const float ro_old = fminf(fmaxf(oo, 0.f), 1.f);
      const float g = (oo >= 0.f && oo <= 1.f) ? (ro_old - bo - s) : 0.f;
      mo = 0.9f * mo + 0.1f * g;
      vo = 0.999f * vo + 0.001f * g * g;
      oo -= eps * (mo * c1) / (sqrtf(vo * c2) + 1e-8f);
      ro_s[t] = fminf(fmaxf(oo, 0.f), 1.f);          // ro(it+1), read next iter
    }

    // ---- prefetch next check's slot (tag it+1, published this iteration).
    //      Loads stay in flight across B3 + next PassB; waited only at the check. ----
    if (t < HID && it + 1 < n_iter) {
      const u64* pn = pbuf + (size_t)(it & (NSLOT - 1)) * (NWG * HID);
#pragma unroll
      for (int wi = 0; wi < 8; ++wi)
        pref[wi] = __hip_atomic_load(&pn[wi * HID + t],
                                     __ATOMIC_RELAXED, __HIP_MEMORY_SCOPE_AGENT);
    }

    bar_lgkm();   // B3: ro_s(it+1) visible for next Pass B
  }

  out[wg * SLICE + t] = oo;
}

// ---------------- launcher ----------------------------------------------------------
extern "C" void kernel_launch(void* const* d_in, const int* in_sizes, int n_in,
                              void* d_out, int out_size, void* d_ws, size_t ws_size,
                              hipStream_t stream) {
  const float* x     = (const float*)d_in[0];
  const float* W1    = (const float*)d_in[1];
  const float* W2    = (const float*)d_in[2];
  // d_in[3] = b_in (unused by the reference)
  const float* b_h   = (const float*)d_in[4];
  const float* b_out = (const float*)d_in[5];
  const float* h0    = (const float*)d_in[6];
  const float* o0    = (const float*)d_in[7];
  const int*   nit   = (const int*)d_in[8];
  const float* eps   = (const float*)d_in[9];

  u64*   pbuf = (u64*)d_ws;                         // [4][8][128] u64 = 32 KB
  u64*   xw1p = (u64*)((char*)d_ws + 32768);        // [128][128] u64 = 128 KB
  float* out  = (float*)d_out;

  // no memset needed: poisoned 0xAAAAAAAA tags never match (xw1 tag=1, iter tags=1..n)
  k_all<<<dim3(NWG + NXB), dim3(NT), 0, stream>>>(x, W1, W2, b_h, b_out, h0, o0,
                                                  nit, eps, pbuf, xw1p, out);
}